// Round 14
// baseline (3560.386 us; speedup 1.0000x reference)
//
#include <hip/hip_runtime.h>
#include <math.h>

// Observer recurrence -> LTI Markov-parameter convolution.
//   A' = A - L*C, K = [B - L*D | L | h0], f_m = C A'^m K
//   y_t = f_t[9] + D*u_t + sum_j f_j . z_{t-1-j};  out = 3*tanh(y)
// Round-22: TLP merge. r13 post-mortem: ~2.8us/step unexplained stall;
// k_stepVR ran 1 wave/SIMD (256 blocks x 256 thr, V and R on DISJOINT CUs)
// so V's 64 serial A-loads/wave expose L2/L3 latency. r6's B-halving null
// showed L2-hit requests are cheap -> latency-bound, not request-bound.
// Now: 256 blocks x 512 thr, EVERY CU gets 4 V-waves (tile b, k-split
// 4x1024 -- r8's validated shape) + 4 R-waves (rows 16b..16b+16).
// R redesign: no LDS reduction at all -- each R-thread owns 16 cols and
// atomicAdd's its fp32 partial into gf[r+1] (1 add/addr/block; device
// scope; order noise ~1e-6). R reads pre-summed gf[r] directly. Single
// common __syncthreads. Rpart buffers deleted. B-broadcast 10->20 MB
// (L2-hit, cheap). V math, A8r/sAg quantization, JT=56, MITM 28+27
// unchanged from r13 (absmax 0.0391).

constexpr int NDIM  = 4096;
constexpr int NC    = 10;         // live columns of K/W
constexpr int SLAB  = 16 * 4096;  // padded 16-col col-major slab (elements)
constexpr int JT    = 56;         // truncation length
constexpr int VAPPS = 28;         // V-chain applications (W_1..W_28)
constexpr int KC    = NDIM / 32;  // 128 k-chunks of 32
constexpr int TILES = NDIM / 16;  // 256 row-tiles of 16

typedef float    f32x4  __attribute__((ext_vector_type(4)));
typedef _Float16 h16x8  __attribute__((ext_vector_type(8)));
typedef _Float16 f16;

// ---------- build A' = A - L*C: fp16 swizzled frags + int8 plain + scales --
// AhSw element (h16x8): idx = (tile*KC + kc)*64 + lane
//   lane = mr + 16q holds A'[tile*16+mr][kc*32 + q*8 .. +7]
// A8r: plain row-major int8, q = round(x * 127 / groupmax(row, 64-col blk))
// sAg[row][g]: groupmax/127 for col-group g (64 cols).
__global__ __launch_bounds__(256) void k_build_a(
        const float* __restrict__ A, const float* __restrict__ C,
        const float* __restrict__ L, h16x8* __restrict__ AhSw,
        signed char* __restrict__ A8r, float* __restrict__ sAg) {
    __shared__ float lds[64][65];
    __shared__ float smax[64];
    const int R0 = (blockIdx.x & 63) * 64;
    const int C0 = (blockIdx.x >> 6) * 64;
    const int tid = threadIdx.x;
    #pragma unroll
    for (int it = 0; it < 16; ++it) {
        const int r = it * 4 + (tid >> 6);
        const int c = tid & 63;
        lds[r][c] = A[(size_t)(R0 + r) * NDIM + C0 + c]
                  - L[R0 + r] * C[C0 + c];
    }
    __syncthreads();
    if (tid < 64) {
        float mx = 0.0f;
        #pragma unroll 8
        for (int c = 0; c < 64; ++c) mx = fmaxf(mx, fabsf(lds[tid][c]));
        smax[tid] = mx;
        sAg[(size_t)(R0 + tid) * 64 + (C0 >> 6)] = mx / 127.0f;
    }
    __syncthreads();
    // int8 emission: thread -> row tid>>2, 16-col segment tid&3
    {
        const int r = tid >> 2, seg = tid & 3;
        const float mx = smax[r];
        const float inv = mx > 0.0f ? 127.0f / mx : 0.0f;
        union { int4 v; signed char c[16]; } uo;
        #pragma unroll
        for (int j = 0; j < 16; ++j) {
            int qv = (int)rintf(lds[r][seg * 16 + j] * inv);
            qv = qv > 127 ? 127 : (qv < -127 ? -127 : qv);
            uo.c[j] = (signed char)qv;
        }
        *(int4*)(A8r + (size_t)(R0 + r) * NDIM + C0 + seg * 16) = uo.v;
    }
    // fp16 frag emission
    #pragma unroll
    for (int half = 0; half < 2; ++half) {
        const int o = half * 256 + tid;
        const int r = o >> 3;
        const int g = o & 7;
        union { h16x8 v; f16 h[8]; } pk;
        #pragma unroll
        for (int j = 0; j < 8; ++j) pk.h[j] = (f16)lds[r][g * 8 + j];
        const int tile = (R0 >> 4) + (r >> 4);
        const int kc   = (C0 >> 5) + (g >> 2);
        const int lane = (r & 15) | ((g & 3) << 4);
        AhSw[((size_t)tile * KC + kc) * 64 + lane] = pk.v;
    }
}

// ---------- W0 = K, fp16; gf[0] = C, gf[1..27] = 0 ----------
__global__ __launch_bounds__(256) void k_build_w0(
        const float* __restrict__ Bm, const float* __restrict__ Dm,
        const float* __restrict__ L, const float* __restrict__ C,
        f16* __restrict__ Wh, float* __restrict__ gf) {
    int k = blockIdx.x * blockDim.x + threadIdx.x; // < 4096
    float Lk = L[k];
    float col[16];
    #pragma unroll
    for (int c = 0; c < 8; ++c) col[c] = Bm[k * 8 + c] - Lk * Dm[c];
    col[8] = Lk; col[9] = 1.0f;
    #pragma unroll
    for (int c = 10; c < 16; ++c) col[c] = 0.0f;
    #pragma unroll
    for (int c = 0; c < 16; ++c) Wh[c * NDIM + k] = (f16)col[c];
    gf[k] = C[k];                                   // g_0 = C
    for (int r = 1; r < VAPPS; ++r) gf[(size_t)r * NDIM + k] = 0.0f;
}

// ---------- fused step: every block has V-waves AND R-waves ----------
// 256 blocks x 512 thr. Waves 0-3: V tile b (k-split 4x1024, fp16 MFMA,
// dead-col skip -- r8-validated). Waves 4-7: R rows [16b,16b+16): read
// pre-summed gf[r], scale by sAg, int8 matvec (16 cols/thread, contiguous
// 16B row loads), atomicAdd fp32 into gf[r+1]. One common barrier.
__global__ __launch_bounds__(512, 1) void k_stepVR(
        const h16x8* __restrict__ AhSw,
        const signed char* __restrict__ A8r, const float* __restrict__ sAg,
        const f16* __restrict__ WhIn, f16* __restrict__ WhOut,
        const float* __restrict__ gIn, float* __restrict__ gNext,
        const int doR) {
    __shared__ f32x4 red[4][64];
    const int tid  = threadIdx.x;
    const int wave = tid >> 6;
    const int b    = blockIdx.x;          // tile / R-unit
    const int row0 = b * 16;

    if (wave < 4) {
        // ---------------- V waves ----------------
        const int lane = tid & 63;
        const int mr   = lane & 15, q = lane >> 4;
        const int k0   = wave * 1024;
        const bool liveB = (mr < NC);
        const h16x8* a8 = AhSw + ((size_t)b * KC + wave * 32) * 64 + lane;
        const h16x8* b8 = (const h16x8*)WhIn + (((size_t)mr * NDIM + k0) >> 3) + q;

        f32x4 acc0 = {0,0,0,0}, acc1 = {0,0,0,0};
        for (int it = 0; it < 4; ++it) {
            h16x8 ra[8], rb[8];
            #pragma unroll
            for (int s = 0; s < 8; ++s) rb[s] = (h16x8){0,0,0,0,0,0,0,0};
            #pragma unroll
            for (int s = 0; s < 8; ++s) {
                const int c = it * 8 + s;           // kc-local 0..31
                ra[s] = a8[(size_t)c * 64];
            }
            if (liveB) {
                #pragma unroll
                for (int s = 0; s < 8; ++s) {
                    const int c = it * 8 + s;
                    rb[s] = b8[c * 4];
                }
            }
            #pragma unroll
            for (int s = 0; s < 8; ++s) {
                if (s & 1) acc1 = __builtin_amdgcn_mfma_f32_16x16x32_f16(ra[s], rb[s], acc1, 0, 0, 0);
                else       acc0 = __builtin_amdgcn_mfma_f32_16x16x32_f16(ra[s], rb[s], acc0, 0, 0, 0);
            }
        }
        red[wave][lane] = acc0 + acc1;
    } else if (doR) {
        // ---------------- R waves ----------------
        const int rt = tid - 256;             // 0..255
        const int c0 = rt * 16;               // this thread's 16 cols
        const int g0 = c0 >> 6;               // 64-col scale group
        float gl[16];
        #pragma unroll
        for (int rr = 0; rr < 16; ++rr)
            gl[rr] = gIn[row0 + rr] * sAg[(size_t)(row0 + rr) * 64 + g0];
        float acc[16] = {};
        const int4* arow = (const int4*)(A8r + (size_t)row0 * NDIM + c0);
        #pragma unroll
        for (int rr = 0; rr < 16; ++rr) {
            const int4 v = arow[(size_t)rr * (NDIM / 16)];
            const float gm = gl[rr];
            const int w0 = v.x, w1 = v.y, w2 = v.z, w3 = v.w;
            #pragma unroll
            for (int bb = 0; bb < 4; ++bb) {
                acc[bb]      += gm * (float)((w0 << (24 - 8 * bb)) >> 24);
                acc[4 + bb]  += gm * (float)((w1 << (24 - 8 * bb)) >> 24);
                acc[8 + bb]  += gm * (float)((w2 << (24 - 8 * bb)) >> 24);
                acc[12 + bb] += gm * (float)((w3 << (24 - 8 * bb)) >> 24);
            }
        }
        float* gn = gNext + c0;
        #pragma unroll
        for (int j = 0; j < 16; ++j) atomicAdd(gn + j, acc[j]);
    }

    __syncthreads();
    if (tid < 64) {
        f32x4 v = red[0][tid] + red[1][tid] + red[2][tid] + red[3][tid];
        const int col = tid & 15;
        if (col < NC) {
            const int rb0 = row0 + ((tid >> 4) << 2);
            #pragma unroll
            for (int i = 0; i < 4; ++i)
                WhOut[col * NDIM + rb0 + i] = (f16)v[i];
        }
    }
}

// ---------- f_m for all m: m<=28 via C.W_m, m=28+i via g_i.W_28 ----------
__global__ __launch_bounds__(256) void k_fbatch(
        const f16* __restrict__ Wh, const float* __restrict__ C,
        const float* __restrict__ gf, float* __restrict__ F) {
    const int m = blockIdx.x;             // 0..JT-1
    const f16* W;
    const float* vec;
    if (m <= VAPPS) { W = Wh + (size_t)m * SLAB;     vec = C; }
    else            { W = Wh + (size_t)VAPPS * SLAB; vec = gf + (size_t)(m - VAPPS) * NDIM; }
    const int tid = threadIdx.x, lane = tid & 63, wave = tid >> 6;
    float acc[NC] = {};
    for (int k = tid; k < NDIM; k += 256) {
        float ck = vec[k];
        #pragma unroll
        for (int c = 0; c < NC; ++c) acc[c] += ck * (float)W[c * NDIM + k];
    }
    __shared__ float red[4][NC];
    #pragma unroll
    for (int c = 0; c < NC; ++c) {
        float s = acc[c];
        #pragma unroll
        for (int off = 32; off > 0; off >>= 1) s += __shfl_down(s, off);
        if (lane == 0) red[wave][c] = s;
    }
    __syncthreads();
    if (tid < NC) F[m * NC + tid] = red[0][tid] + red[1][tid] + red[2][tid] + red[3][tid];
}

// ---------- causal convolution + tanh epilogue ----------
__global__ __launch_bounds__(256) void k_conv(
        const float* __restrict__ F, const float* __restrict__ u,
        const float* __restrict__ yobs, const float* __restrict__ Dm,
        float* __restrict__ out) {
    __shared__ float Fl[JT * NC];
    __shared__ float zw[(JT + 256) * 9];
    const int tid = threadIdx.x;
    const int t0  = blockIdx.x * 256;
    for (int idx = tid; idx < JT * NC; idx += 256) Fl[idx] = F[idx];
    for (int idx = tid; idx < (JT + 256) * 9; idx += 256) {
        int k = idx / 9, c = idx - k * 9;
        int s = t0 - JT + k;
        float v = 0.0f;
        if (s >= 0 && s < NDIM) v = (c < 8) ? u[c * NDIM + s] : yobs[s];
        zw[idx] = v;
    }
    __syncthreads();
    const int t = t0 + tid;
    float y = (t < JT) ? Fl[t * NC + 9] : 0.0f; // C A'^t h0 term (truncated)
    #pragma unroll
    for (int c = 0; c < 8; ++c) y += Dm[c] * u[c * NDIM + t];
    for (int j = 0; j < JT; ++j) { // s = t-1-j; s<0 hits zero pad
        const float* fj = Fl + j * NC;
        const float* zz = zw + (tid + JT - 1 - j) * 9;
        float p = 0.0f;
        #pragma unroll
        for (int c = 0; c < 9; ++c) p += fj[c] * zz[c];
        y += p;
    }
    out[t] = 3.0f * tanhf(y);
}

extern "C" void kernel_launch(void* const* d_in, const int* in_sizes, int n_in,
                              void* d_out, int out_size, void* d_ws, size_t ws_size,
                              hipStream_t stream) {
    const float* u    = (const float*)d_in[0];
    const float* yobs = (const float*)d_in[1];
    const float* A    = (const float*)d_in[2];
    const float* Bm   = (const float*)d_in[3];
    const float* C    = (const float*)d_in[4];
    const float* Dm   = (const float*)d_in[5];
    const float* L    = (const float*)d_in[6];
    float* out = (float*)d_out;

    // workspace layout (~56 MB)
    char* ws = (char*)d_ws;
    h16x8*       AhSw = (h16x8*)ws;                        // 32 MB
    signed char* A8r  = (signed char*)(ws + 33554432ull);  // 16 MB
    float*       sAg  = (float*)(ws + 50331648ull);        // 1 MB (4096x64)
    f16*         Wh   = (f16*)(ws + 51380224ull);          // 29*128 KB
    float*       gf   = (float*)(ws + 55181312ull);        // 28*16 KB
    float*       F    = (float*)(ws + 55640064ull);        // 2.24 KB

    k_build_w0<<<dim3(16), dim3(256), 0, stream>>>(Bm, Dm, L, C, Wh, gf);
    k_build_a<<<dim3(64 * 64), dim3(256), 0, stream>>>(A, C, L, AhSw, A8r, sAg);

    for (int r = 0; r < VAPPS; ++r) {
        const size_t in   = (size_t)r * SLAB;
        const size_t out_ = (size_t)(r + 1) * SLAB;
        const int doR = (r < VAPPS - 1) ? 1 : 0;
        k_stepVR<<<dim3(TILES), dim3(512), 0, stream>>>(
            AhSw, A8r, sAg, Wh + in, Wh + out_,
            gf + (size_t)r * NDIM, gf + (size_t)(r + 1) * NDIM, doR);
    }

    k_fbatch<<<dim3(JT), dim3(256), 0, stream>>>(Wh, C, gf, F);
    k_conv<<<dim3(16), dim3(256), 0, stream>>>(F, u, yobs, Dm, out);
}

// Round 15
// 463.477 us; speedup vs baseline: 7.6819x; 7.6819x over previous
//
#include <hip/hip_runtime.h>
#include <math.h>

// Observer recurrence -> LTI Markov-parameter convolution.
//   A' = A - L*C, K = [B - L*D | L | h0], f_m = C A'^m K
//   y_t = f_t[9] + D*u_t + sum_j f_j . z_{t-1-j};  out = 3*tanh(y)
// Round-23: TLP merge, atomics removed. r14's 3560us was 1M device-scope
// atomicAdds/step (256 adds per gf address) serializing at the coherence
// point -- a bug, not a theory test. Same merge now with r13's partials:
//   256 blocks x 512 thr (2 waves/SIMD). Waves 0-3: V tile b (k-split
//   4x1024 fp16 MFMA, dead-col skip -- r8/r14-validated shape, r14 passed
//   correctness). Waves 4-7: R rows [16b,16b+16): reduce prev partials
//   WAVE-LOCALLY (each lane sums 4 partial rows, 6-round __shfl_xor
//   butterfly; all 4 R-waves redundant -> zero extra barriers), int8
//   matvec (16 cols/thread), write ONE fp16 partial row Rpart[b][*]
//   (plain stores). Single final __syncthreads (V fold) as before.
// Bytes ~ r13 (B 10.5->20 MB L2-hit, proven cheap in r6; Rpart 2->4 MB).
// Clean A/B of 2-wave/SIMD TLP vs r13's 1-wave/SIMD at equal bytes.
// Predicted: TLP right -> ~360-400us; >=425 -> r13 is the floor.

constexpr int NDIM  = 4096;
constexpr int NC    = 10;         // live columns of K/W
constexpr int SLAB  = 16 * 4096;  // padded 16-col col-major slab (elements)
constexpr int JT    = 56;         // truncation length
constexpr int VAPPS = 28;         // V-chain applications (W_1..W_28)
constexpr int KC    = NDIM / 32;  // 128 k-chunks of 32
constexpr int TILES = NDIM / 16;  // 256 row-tiles of 16

typedef float    f32x4  __attribute__((ext_vector_type(4)));
typedef _Float16 h16x8  __attribute__((ext_vector_type(8)));
typedef _Float16 f16;

// ---------- build A' = A - L*C: fp16 swizzled frags + int8 plain + scales --
// AhSw element (h16x8): idx = (tile*KC + kc)*64 + lane
//   lane = mr + 16q holds A'[tile*16+mr][kc*32 + q*8 .. +7]
// A8r: plain row-major int8, q = round(x * 127 / groupmax(row, 64-col blk))
// sAg[row][g]: groupmax/127 for col-group g (64 cols).
__global__ __launch_bounds__(256) void k_build_a(
        const float* __restrict__ A, const float* __restrict__ C,
        const float* __restrict__ L, h16x8* __restrict__ AhSw,
        signed char* __restrict__ A8r, float* __restrict__ sAg) {
    __shared__ float lds[64][65];
    __shared__ float smax[64];
    const int R0 = (blockIdx.x & 63) * 64;
    const int C0 = (blockIdx.x >> 6) * 64;
    const int tid = threadIdx.x;
    #pragma unroll
    for (int it = 0; it < 16; ++it) {
        const int r = it * 4 + (tid >> 6);
        const int c = tid & 63;
        lds[r][c] = A[(size_t)(R0 + r) * NDIM + C0 + c]
                  - L[R0 + r] * C[C0 + c];
    }
    __syncthreads();
    if (tid < 64) {
        float mx = 0.0f;
        #pragma unroll 8
        for (int c = 0; c < 64; ++c) mx = fmaxf(mx, fabsf(lds[tid][c]));
        smax[tid] = mx;
        sAg[(size_t)(R0 + tid) * 64 + (C0 >> 6)] = mx / 127.0f;
    }
    __syncthreads();
    // int8 emission: thread -> row tid>>2, 16-col segment tid&3
    {
        const int r = tid >> 2, seg = tid & 3;
        const float mx = smax[r];
        const float inv = mx > 0.0f ? 127.0f / mx : 0.0f;
        union { int4 v; signed char c[16]; } uo;
        #pragma unroll
        for (int j = 0; j < 16; ++j) {
            int qv = (int)rintf(lds[r][seg * 16 + j] * inv);
            qv = qv > 127 ? 127 : (qv < -127 ? -127 : qv);
            uo.c[j] = (signed char)qv;
        }
        *(int4*)(A8r + (size_t)(R0 + r) * NDIM + C0 + seg * 16) = uo.v;
    }
    // fp16 frag emission
    #pragma unroll
    for (int half = 0; half < 2; ++half) {
        const int o = half * 256 + tid;
        const int r = o >> 3;
        const int g = o & 7;
        union { h16x8 v; f16 h[8]; } pk;
        #pragma unroll
        for (int j = 0; j < 8; ++j) pk.h[j] = (f16)lds[r][g * 8 + j];
        const int tile = (R0 >> 4) + (r >> 4);
        const int kc   = (C0 >> 5) + (g >> 2);
        const int lane = (r & 15) | ((g & 3) << 4);
        AhSw[((size_t)tile * KC + kc) * 64 + lane] = pk.v;
    }
}

// ---------- W0 = K = [B-L*D | L | ones | 0-pad], fp16 ----------
__global__ __launch_bounds__(256) void k_build_w0(
        const float* __restrict__ Bm, const float* __restrict__ Dm,
        const float* __restrict__ L, f16* __restrict__ Wh) {
    int k = blockIdx.x * blockDim.x + threadIdx.x; // < 4096
    float Lk = L[k];
    float col[16];
    #pragma unroll
    for (int c = 0; c < 8; ++c) col[c] = Bm[k * 8 + c] - Lk * Dm[c];
    col[8] = Lk; col[9] = 1.0f;
    #pragma unroll
    for (int c = 10; c < 16; ++c) col[c] = 0.0f;
    #pragma unroll
    for (int c = 0; c < 16; ++c) Wh[c * NDIM + k] = (f16)col[c];
}

// ---------- fused step: every block has V-waves AND R-waves ----------
// 256 blocks x 512 thr. Waves 0-3: V tile b. Waves 4-7: R rows
// [16b,16b+16): wave-local reduce of 256 fp16 partials (no barrier),
// int8 matvec, plain-store one fp16 partial row. One final barrier (V).
__global__ __launch_bounds__(512, 1) void k_stepVR(
        const h16x8* __restrict__ AhSw,
        const signed char* __restrict__ A8r, const float* __restrict__ sAg,
        const f16* __restrict__ WhIn, f16* __restrict__ WhOut,
        const float* __restrict__ Cvec,
        const f16* __restrict__ RpartIn, f16* __restrict__ RpartOut,
        float* __restrict__ gfSlot, const int r) {
    __shared__ f32x4 red[4][64];
    const int tid  = threadIdx.x;
    const int wave = tid >> 6;
    const int b    = blockIdx.x;          // tile / R-unit
    const int row0 = b * 16;

    if (wave < 4) {
        // ---------------- V waves (r8/r14-validated shape) ----------------
        const int lane = tid & 63;
        const int mr   = lane & 15, q = lane >> 4;
        const int k0   = wave * 1024;
        const bool liveB = (mr < NC);
        const h16x8* a8 = AhSw + ((size_t)b * KC + wave * 32) * 64 + lane;
        const h16x8* b8 = (const h16x8*)WhIn + (((size_t)mr * NDIM + k0) >> 3) + q;

        f32x4 acc0 = {0,0,0,0}, acc1 = {0,0,0,0};
        for (int it = 0; it < 4; ++it) {
            h16x8 ra[8], rb[8];
            #pragma unroll
            for (int s = 0; s < 8; ++s) rb[s] = (h16x8){0,0,0,0,0,0,0,0};
            #pragma unroll
            for (int s = 0; s < 8; ++s) {
                const int c = it * 8 + s;           // kc-local 0..31
                ra[s] = a8[(size_t)c * 64];
            }
            if (liveB) {
                #pragma unroll
                for (int s = 0; s < 8; ++s) {
                    const int c = it * 8 + s;
                    rb[s] = b8[c * 4];
                }
            }
            #pragma unroll
            for (int s = 0; s < 8; ++s) {
                if (s & 1) acc1 = __builtin_amdgcn_mfma_f32_16x16x32_f16(ra[s], rb[s], acc1, 0, 0, 0);
                else       acc0 = __builtin_amdgcn_mfma_f32_16x16x32_f16(ra[s], rb[s], acc0, 0, 0, 0);
            }
        }
        red[wave][lane] = acc0 + acc1;
    } else {
        // ---------------- R waves ----------------
        const int lane = tid & 63;
        float gs[16];
        if (r == 0) {
            #pragma unroll
            for (int j = 0; j < 16; ++j) gs[j] = Cvec[row0 + j];
        } else {
            // wave-local reduction of 256 partials x 16 cols (redundant
            // in each of the 4 R-waves; no cross-wave barrier needed)
            float s[16] = {};
            #pragma unroll
            for (int pp = 0; pp < 4; ++pp) {
                const int p = lane + pp * 64;
                const h16x8* src = (const h16x8*)(RpartIn + (size_t)p * NDIM + row0);
                h16x8 v0 = src[0], v1 = src[1];
                #pragma unroll
                for (int j = 0; j < 8; ++j) {
                    s[j]     += (float)v0[j];
                    s[8 + j] += (float)v1[j];
                }
            }
            #pragma unroll
            for (int off = 32; off > 0; off >>= 1) {
                #pragma unroll
                for (int j = 0; j < 16; ++j) s[j] += __shfl_xor(s[j], off);
            }
            #pragma unroll
            for (int j = 0; j < 16; ++j) gs[j] = s[j];
        }
        if (wave == 4 && lane < 16) gfSlot[row0 + lane] = gs[lane];

        if (r < VAPPS - 1) {
            const int rt = tid - 256;             // 0..255
            const int c0 = rt * 16;               // this thread's 16 cols
            const int g0 = rt >> 2;               // 64-col scale group
            float gl[16];
            #pragma unroll
            for (int rr = 0; rr < 16; ++rr)
                gl[rr] = gs[rr] * sAg[(size_t)(row0 + rr) * 64 + g0];
            float acc[16] = {};
            const int4* arow = (const int4*)(A8r + (size_t)row0 * NDIM + c0);
            #pragma unroll
            for (int rr = 0; rr < 16; ++rr) {
                const int4 v = arow[(size_t)rr * (NDIM / 16)];
                const float gm = gl[rr];
                const int w0 = v.x, w1 = v.y, w2 = v.z, w3 = v.w;
                #pragma unroll
                for (int bb = 0; bb < 4; ++bb) {
                    acc[bb]      += gm * (float)((w0 << (24 - 8 * bb)) >> 24);
                    acc[4 + bb]  += gm * (float)((w1 << (24 - 8 * bb)) >> 24);
                    acc[8 + bb]  += gm * (float)((w2 << (24 - 8 * bb)) >> 24);
                    acc[12 + bb] += gm * (float)((w3 << (24 - 8 * bb)) >> 24);
                }
            }
            union { h16x8 h; int4 i4; } o0, o1;
            #pragma unroll
            for (int j = 0; j < 8; ++j) {
                o0.h[j] = (f16)acc[j];
                o1.h[j] = (f16)acc[8 + j];
            }
            h16x8* op = (h16x8*)(RpartOut + (size_t)b * NDIM + c0);
            op[0] = o0.h;
            op[1] = o1.h;
        }
    }

    __syncthreads();
    if (tid < 64) {
        f32x4 v = red[0][tid] + red[1][tid] + red[2][tid] + red[3][tid];
        const int col = tid & 15;
        if (col < NC) {
            const int rb0 = row0 + ((tid >> 4) << 2);
            #pragma unroll
            for (int i = 0; i < 4; ++i)
                WhOut[col * NDIM + rb0 + i] = (f16)v[i];
        }
    }
}

// ---------- f_m for all m: m<=28 via C.W_m, m=28+i via g_i.W_28 ----------
__global__ __launch_bounds__(256) void k_fbatch(
        const f16* __restrict__ Wh, const float* __restrict__ C,
        const float* __restrict__ gf, float* __restrict__ F) {
    const int m = blockIdx.x;             // 0..JT-1
    const f16* W;
    const float* vec;
    if (m <= VAPPS) { W = Wh + (size_t)m * SLAB;     vec = C; }
    else            { W = Wh + (size_t)VAPPS * SLAB; vec = gf + (size_t)(m - VAPPS) * NDIM; }
    const int tid = threadIdx.x, lane = tid & 63, wave = tid >> 6;
    float acc[NC] = {};
    for (int k = tid; k < NDIM; k += 256) {
        float ck = vec[k];
        #pragma unroll
        for (int c = 0; c < NC; ++c) acc[c] += ck * (float)W[c * NDIM + k];
    }
    __shared__ float red[4][NC];
    #pragma unroll
    for (int c = 0; c < NC; ++c) {
        float s = acc[c];
        #pragma unroll
        for (int off = 32; off > 0; off >>= 1) s += __shfl_down(s, off);
        if (lane == 0) red[wave][c] = s;
    }
    __syncthreads();
    if (tid < NC) F[m * NC + tid] = red[0][tid] + red[1][tid] + red[2][tid] + red[3][tid];
}

// ---------- causal convolution + tanh epilogue ----------
__global__ __launch_bounds__(256) void k_conv(
        const float* __restrict__ F, const float* __restrict__ u,
        const float* __restrict__ yobs, const float* __restrict__ Dm,
        float* __restrict__ out) {
    __shared__ float Fl[JT * NC];
    __shared__ float zw[(JT + 256) * 9];
    const int tid = threadIdx.x;
    const int t0  = blockIdx.x * 256;
    for (int idx = tid; idx < JT * NC; idx += 256) Fl[idx] = F[idx];
    for (int idx = tid; idx < (JT + 256) * 9; idx += 256) {
        int k = idx / 9, c = idx - k * 9;
        int s = t0 - JT + k;
        float v = 0.0f;
        if (s >= 0 && s < NDIM) v = (c < 8) ? u[c * NDIM + s] : yobs[s];
        zw[idx] = v;
    }
    __syncthreads();
    const int t = t0 + tid;
    float y = (t < JT) ? Fl[t * NC + 9] : 0.0f; // C A'^t h0 term (truncated)
    #pragma unroll
    for (int c = 0; c < 8; ++c) y += Dm[c] * u[c * NDIM + t];
    for (int j = 0; j < JT; ++j) { // s = t-1-j; s<0 hits zero pad
        const float* fj = Fl + j * NC;
        const float* zz = zw + (tid + JT - 1 - j) * 9;
        float p = 0.0f;
        #pragma unroll
        for (int c = 0; c < 9; ++c) p += fj[c] * zz[c];
        y += p;
    }
    out[t] = 3.0f * tanhf(y);
}

extern "C" void kernel_launch(void* const* d_in, const int* in_sizes, int n_in,
                              void* d_out, int out_size, void* d_ws, size_t ws_size,
                              hipStream_t stream) {
    const float* u    = (const float*)d_in[0];
    const float* yobs = (const float*)d_in[1];
    const float* A    = (const float*)d_in[2];
    const float* Bm   = (const float*)d_in[3];
    const float* C    = (const float*)d_in[4];
    const float* Dm   = (const float*)d_in[5];
    const float* L    = (const float*)d_in[6];
    float* out = (float*)d_out;

    // workspace layout (~60 MB)
    char* ws = (char*)d_ws;
    h16x8*       AhSw  = (h16x8*)ws;                        // 32 MB
    signed char* A8r   = (signed char*)(ws + 33554432ull);  // 16 MB
    float*       sAg   = (float*)(ws + 50331648ull);        // 1 MB (4096x64)
    f16*         Wh    = (f16*)(ws + 51380224ull);          // 29*128 KB
    float*       gf    = (float*)(ws + 55181312ull);        // 28*16 KB
    f16*         RpartH= (f16*)(ws + 55640064ull);          // 2*2 MB (ping-pong)
    float*       F     = (float*)(ws + 59834368ull);        // 2.24 KB

    constexpr size_t RPN = (size_t)256 * NDIM;   // one Rpart buffer (f16 elems)

    k_build_w0<<<dim3(16), dim3(256), 0, stream>>>(Bm, Dm, L, Wh);
    k_build_a<<<dim3(64 * 64), dim3(256), 0, stream>>>(A, C, L, AhSw, A8r, sAg);

    for (int r = 0; r < VAPPS; ++r) {
        const size_t in   = (size_t)r * SLAB;
        const size_t out_ = (size_t)(r + 1) * SLAB;
        const f16* rin  = RpartH + ((r + 1) & 1) * RPN;
        f16*       rout = RpartH + (r & 1) * RPN;
        k_stepVR<<<dim3(TILES), dim3(512), 0, stream>>>(
            AhSw, A8r, sAg, Wh + in, Wh + out_,
            C, rin, rout, gf + (size_t)r * NDIM, r);
    }

    k_fbatch<<<dim3(JT), dim3(256), 0, stream>>>(Wh, C, gf, F);
    k_conv<<<dim3(16), dim3(256), 0, stream>>>(F, u, yobs, Dm, out);
}

// Round 16
// 425.458 us; speedup vs baseline: 8.3684x; 1.0894x over previous
//
#include <hip/hip_runtime.h>
#include <math.h>

// Observer recurrence -> LTI Markov-parameter convolution.
//   A' = A - L*C, K = [B - L*D | L | h0], f_m = C A'^m K
//   y_t = f_t[9] + D*u_t + sum_j f_j . z_{t-1-j};  out = 3*tanh(y)
// Round-24: REVERT to r13 (425.9us best; r15's TLP merge was -37us, TLP
// direction dead) + one targeted fix from r15's profile: k_build_a ran
// 42us at 2.0 TB/s (25% HBM) because its A-read was one scalar
// row-segment per wave instruction (256B). Now float4 loads (4 rows /
// 1KB per wave instruction), A - L*C folded into the same pass. The
// staged lds[][] values are computed with IDENTICAL arithmetic; all
// emission phases and every chain kernel are byte-identical to r13 ->
// absmax must reproduce 0.0391. Everything else: r13 exact (V fp16 MFMA
// 128 blocks x 2 tiles + R int8 matvec w/ per-64col-group scales, fp16
// Rpart, fbatch from Wh, MITM 28+27, JT=56).
// Predicted: build 42 -> ~22-27us; total 426 -> ~405-415.

constexpr int NDIM  = 4096;
constexpr int NC    = 10;         // live columns of K/W
constexpr int SLAB  = 16 * 4096;  // padded 16-col col-major slab (elements)
constexpr int JT    = 56;         // truncation length
constexpr int VAPPS = 28;         // V-chain applications (W_1..W_28)
constexpr int KC    = NDIM / 32;  // 128 k-chunks of 32
constexpr int TILES = NDIM / 16;  // 256 row-tiles of 16

typedef float    f32x4  __attribute__((ext_vector_type(4)));
typedef _Float16 h16x8  __attribute__((ext_vector_type(8)));
typedef _Float16 f16;

// ---------- build A' = A - L*C: fp16 swizzled frags + int8 plain + scales --
// AhSw element (h16x8): idx = (tile*KC + kc)*64 + lane
//   lane = mr + 16q holds A'[tile*16+mr][kc*32 + q*8 .. +7]
// A8r: plain row-major int8, q = round(x * 127 / groupmax(row, 64-col blk))
// sAg[row][g]: groupmax/127 for col-group g (64 cols).
// Load phase: float4 (1KB per wave instruction; was 256B scalar -> 2.0TB/s).
__global__ __launch_bounds__(256) void k_build_a(
        const float* __restrict__ A, const float* __restrict__ C,
        const float* __restrict__ L, h16x8* __restrict__ AhSw,
        signed char* __restrict__ A8r, float* __restrict__ sAg) {
    __shared__ float lds[64][65];
    __shared__ float smax[64];
    const int R0 = (blockIdx.x & 63) * 64;
    const int C0 = (blockIdx.x >> 6) * 64;
    const int tid = threadIdx.x;
    #pragma unroll
    for (int it = 0; it < 4; ++it) {
        const int o  = it * 256 + tid;      // 0..1023
        const int r  = o >> 4;              // 0..63
        const int c4 = (o & 15) * 4;        // 0,4,...,60
        const float4 a = *(const float4*)(A + (size_t)(R0 + r) * NDIM + C0 + c4);
        const float Li = L[R0 + r];
        lds[r][c4]     = a.x - Li * C[C0 + c4];
        lds[r][c4 + 1] = a.y - Li * C[C0 + c4 + 1];
        lds[r][c4 + 2] = a.z - Li * C[C0 + c4 + 2];
        lds[r][c4 + 3] = a.w - Li * C[C0 + c4 + 3];
    }
    __syncthreads();
    if (tid < 64) {
        float mx = 0.0f;
        #pragma unroll 8
        for (int c = 0; c < 64; ++c) mx = fmaxf(mx, fabsf(lds[tid][c]));
        smax[tid] = mx;
        sAg[(size_t)(R0 + tid) * 64 + (C0 >> 6)] = mx / 127.0f;
    }
    __syncthreads();
    // int8 emission: thread -> row tid>>2, 16-col segment tid&3
    {
        const int r = tid >> 2, seg = tid & 3;
        const float mx = smax[r];
        const float inv = mx > 0.0f ? 127.0f / mx : 0.0f;
        union { int4 v; signed char c[16]; } uo;
        #pragma unroll
        for (int j = 0; j < 16; ++j) {
            int qv = (int)rintf(lds[r][seg * 16 + j] * inv);
            qv = qv > 127 ? 127 : (qv < -127 ? -127 : qv);
            uo.c[j] = (signed char)qv;
        }
        *(int4*)(A8r + (size_t)(R0 + r) * NDIM + C0 + seg * 16) = uo.v;
    }
    // fp16 frag emission (r13-identical)
    #pragma unroll
    for (int half = 0; half < 2; ++half) {
        const int o = half * 256 + tid;
        const int r = o >> 3;
        const int g = o & 7;
        union { h16x8 v; f16 h[8]; } pk;
        #pragma unroll
        for (int j = 0; j < 8; ++j) pk.h[j] = (f16)lds[r][g * 8 + j];
        const int tile = (R0 >> 4) + (r >> 4);
        const int kc   = (C0 >> 5) + (g >> 2);
        const int lane = (r & 15) | ((g & 3) << 4);
        AhSw[((size_t)tile * KC + kc) * 64 + lane] = pk.v;
    }
}

// ---------- W0 = K = [B-L*D | L | ones | 0-pad], fp16 ----------
__global__ __launch_bounds__(256) void k_build_w0(
        const float* __restrict__ Bm, const float* __restrict__ Dm,
        const float* __restrict__ L, f16* __restrict__ Wh) {
    int k = blockIdx.x * blockDim.x + threadIdx.x; // < 4096
    float Lk = L[k];
    float col[16];
    #pragma unroll
    for (int c = 0; c < 8; ++c) col[c] = Bm[k * 8 + c] - Lk * Dm[c];
    col[8] = Lk; col[9] = 1.0f;
    #pragma unroll
    for (int c = 10; c < 16; ++c) col[c] = 0.0f;
    #pragma unroll
    for (int c = 0; c < 16; ++c) Wh[c * NDIM + k] = (f16)col[c];
}

// ---------- fused step: V-role (blocks 0..127) + R-role (blocks 128..255) --
// V: block tp owns tiles 2tp,2tp+1; wave w: tile 2tp+(w>>1), k-half (w&1);
//    fp16 MFMA, dead-col skip (r6/r12 exact). Epilogue writes Wh only.
// R: block t owns rows [32t,32t+32): reduce 128 fp16 partials, emit g_r,
//    next partials from int8 A8r with per-group scales (gsc staged in LDS).
__global__ __launch_bounds__(256) void k_stepVR(
        const h16x8* __restrict__ AhSw,
        const signed char* __restrict__ A8r, const float* __restrict__ sAg,
        const f16* __restrict__ WhIn, f16* __restrict__ WhOut,
        const float* __restrict__ Cvec,
        const f16* __restrict__ RpartIn, f16* __restrict__ RpartOut,
        float* __restrict__ gfSlot, const int r) {
    const int tid = threadIdx.x;

    if (blockIdx.x < 128) {
        // ---------------- V role ----------------
        __shared__ f32x4 red[4][64];
        const int lane = tid & 63, wave = tid >> 6;
        const int mr   = lane & 15, q = lane >> 4;
        const int tp   = blockIdx.x;
        const int tile = tp * 2 + (wave >> 1);
        const int kh   = wave & 1;
        const int k0   = kh * 2048;
        const bool liveB = (mr < NC);
        const h16x8* a8 = AhSw + ((size_t)tile * KC + (size_t)kh * 64) * 64 + lane;
        const h16x8* b8 = (const h16x8*)WhIn + (((size_t)mr * NDIM + k0) >> 3) + q;

        f32x4 acc0 = {0,0,0,0}, acc1 = {0,0,0,0};
        for (int it = 0; it < 8; ++it) {
            h16x8 ra[8], rb[8];
            #pragma unroll
            for (int s = 0; s < 8; ++s) rb[s] = (h16x8){0,0,0,0,0,0,0,0};
            #pragma unroll
            for (int s = 0; s < 8; ++s) {
                const int c = it * 8 + s;           // kc-local 0..63
                ra[s] = a8[(size_t)c * 64];
            }
            if (liveB) {
                #pragma unroll
                for (int s = 0; s < 8; ++s) {
                    const int c = it * 8 + s;
                    rb[s] = b8[c * 4];
                }
            }
            #pragma unroll
            for (int s = 0; s < 8; ++s) {
                if (s & 1) acc1 = __builtin_amdgcn_mfma_f32_16x16x32_f16(ra[s], rb[s], acc1, 0, 0, 0);
                else       acc0 = __builtin_amdgcn_mfma_f32_16x16x32_f16(ra[s], rb[s], acc0, 0, 0, 0);
            }
        }
        red[wave][lane] = acc0 + acc1;
        __syncthreads();
        if (tid < 128) {
            const int half = tid >> 6;          // 0: tile 2tp, 1: tile 2tp+1
            const int l    = tid & 63;
            f32x4 v = red[half * 2][l] + red[half * 2 + 1][l];
            const int col = l & 15;
            if (col < NC) {
                const int row0 = (tp * 2 + half) * 16;
                const int rb0  = row0 + ((l >> 4) << 2);
                #pragma unroll
                for (int i = 0; i < 4; ++i)
                    WhOut[col * NDIM + rb0 + i] = (f16)v[i];
            }
        }
    } else {
        // ---------------- R role ----------------
        __shared__ f16   rp[128][32];   // fp16 partials, 8 KB
        __shared__ float g8[8][33];
        __shared__ float gs[32];
        __shared__ float gsc[32][64];   // gs[rr] * sAg[row][g], 8 KB
        const int t = blockIdx.x - 128;  // rows [32t, 32t+32)

        if (r == 0) {
            if (tid < 32) gs[tid] = Cvec[t * 32 + tid];
        } else {
            {
                const int p = tid >> 1, half = tid & 1;
                const h16x8* src = (const h16x8*)(RpartIn
                        + (size_t)p * NDIM + t * 32 + half * 16);
                h16x8 v0 = src[0], v1 = src[1];
                *(h16x8*)&rp[p][half * 16]     = v0;
                *(h16x8*)&rp[p][half * 16 + 8] = v1;
            }
            __syncthreads();
            {
                const int c = tid & 31, g = tid >> 5;   // 8 groups x 32 cols
                float s = 0.0f;
                #pragma unroll
                for (int j = 0; j < 16; ++j) s += (float)rp[g * 16 + j][c];
                g8[g][c] = s;
            }
            __syncthreads();
            if (tid < 32) {
                float s = 0.0f;
                #pragma unroll
                for (int g = 0; g < 8; ++g) s += g8[g][tid];
                gs[tid] = s;
            }
        }
        __syncthreads();
        if (tid < 32) gfSlot[t * 32 + tid] = gs[tid];

        if (r < VAPPS - 1) {
            // stage gs[rr] * sAg[(32t+rr)][g] into LDS
            #pragma unroll
            for (int i = 0; i < 8; ++i) {
                const int idx = tid + i * 256;          // 0..2047
                const int rr = idx >> 6, g = idx & 63;
                gsc[rr][g] = gs[rr] * sAg[(size_t)(t * 32 + rr) * 64 + g];
            }
            __syncthreads();
            const int c0 = tid * 16;            // 16 cols per thread
            const int g0 = tid >> 2;            // col-group (fixed per thread)
            float acc[16] = {};
            const int4* arow = (const int4*)(A8r + (size_t)(t * 32) * NDIM + c0);
            for (int rr = 0; rr < 32; ++rr) {
                const int4 v = arow[(size_t)rr * (NDIM / 16)];
                const float gm = gsc[rr][g0];
                const int w0 = v.x, w1 = v.y, w2 = v.z, w3 = v.w;
                #pragma unroll
                for (int b = 0; b < 4; ++b) {
                    acc[b]      += gm * (float)((w0 << (24 - 8 * b)) >> 24);
                    acc[4 + b]  += gm * (float)((w1 << (24 - 8 * b)) >> 24);
                    acc[8 + b]  += gm * (float)((w2 << (24 - 8 * b)) >> 24);
                    acc[12 + b] += gm * (float)((w3 << (24 - 8 * b)) >> 24);
                }
            }
            union { h16x8 h; int4 i4; } o0, o1;
            #pragma unroll
            for (int j = 0; j < 8; ++j) {
                o0.h[j] = (f16)acc[j];
                o1.h[j] = (f16)acc[8 + j];
            }
            h16x8* op = (h16x8*)(RpartOut + (size_t)t * NDIM + c0);
            op[0] = o0.h;
            op[1] = o1.h;
        }
    }
}

// ---------- f_m for all m: m<=28 via C.W_m, m=28+i via g_i.W_28 ----------
__global__ __launch_bounds__(256) void k_fbatch(
        const f16* __restrict__ Wh, const float* __restrict__ C,
        const float* __restrict__ gf, float* __restrict__ F) {
    const int m = blockIdx.x;             // 0..JT-1
    const f16* W;
    const float* vec;
    if (m <= VAPPS) { W = Wh + (size_t)m * SLAB;     vec = C; }
    else            { W = Wh + (size_t)VAPPS * SLAB; vec = gf + (size_t)(m - VAPPS) * NDIM; }
    const int tid = threadIdx.x, lane = tid & 63, wave = tid >> 6;
    float acc[NC] = {};
    for (int k = tid; k < NDIM; k += 256) {
        float ck = vec[k];
        #pragma unroll
        for (int c = 0; c < NC; ++c) acc[c] += ck * (float)W[c * NDIM + k];
    }
    __shared__ float red[4][NC];
    #pragma unroll
    for (int c = 0; c < NC; ++c) {
        float s = acc[c];
        #pragma unroll
        for (int off = 32; off > 0; off >>= 1) s += __shfl_down(s, off);
        if (lane == 0) red[wave][c] = s;
    }
    __syncthreads();
    if (tid < NC) F[m * NC + tid] = red[0][tid] + red[1][tid] + red[2][tid] + red[3][tid];
}

// ---------- causal convolution + tanh epilogue ----------
__global__ __launch_bounds__(256) void k_conv(
        const float* __restrict__ F, const float* __restrict__ u,
        const float* __restrict__ yobs, const float* __restrict__ Dm,
        float* __restrict__ out) {
    __shared__ float Fl[JT * NC];
    __shared__ float zw[(JT + 256) * 9];
    const int tid = threadIdx.x;
    const int t0  = blockIdx.x * 256;
    for (int idx = tid; idx < JT * NC; idx += 256) Fl[idx] = F[idx];
    for (int idx = tid; idx < (JT + 256) * 9; idx += 256) {
        int k = idx / 9, c = idx - k * 9;
        int s = t0 - JT + k;
        float v = 0.0f;
        if (s >= 0 && s < NDIM) v = (c < 8) ? u[c * NDIM + s] : yobs[s];
        zw[idx] = v;
    }
    __syncthreads();
    const int t = t0 + tid;
    float y = (t < JT) ? Fl[t * NC + 9] : 0.0f; // C A'^t h0 term (truncated)
    #pragma unroll
    for (int c = 0; c < 8; ++c) y += Dm[c] * u[c * NDIM + t];
    for (int j = 0; j < JT; ++j) { // s = t-1-j; s<0 hits zero pad
        const float* fj = Fl + j * NC;
        const float* zz = zw + (tid + JT - 1 - j) * 9;
        float p = 0.0f;
        #pragma unroll
        for (int c = 0; c < 9; ++c) p += fj[c] * zz[c];
        y += p;
    }
    out[t] = 3.0f * tanhf(y);
}

extern "C" void kernel_launch(void* const* d_in, const int* in_sizes, int n_in,
                              void* d_out, int out_size, void* d_ws, size_t ws_size,
                              hipStream_t stream) {
    const float* u    = (const float*)d_in[0];
    const float* yobs = (const float*)d_in[1];
    const float* A    = (const float*)d_in[2];
    const float* Bm   = (const float*)d_in[3];
    const float* C    = (const float*)d_in[4];
    const float* Dm   = (const float*)d_in[5];
    const float* L    = (const float*)d_in[6];
    float* out = (float*)d_out;

    // workspace layout (~58 MB)
    char* ws = (char*)d_ws;
    h16x8*       AhSw  = (h16x8*)ws;                        // 32 MB
    signed char* A8r   = (signed char*)(ws + 33554432ull);  // 16 MB
    float*       sAg   = (float*)(ws + 50331648ull);        // 1 MB (4096x64)
    f16*         Wh    = (f16*)(ws + 51380224ull);          // 29*128 KB
    float*       gf    = (float*)(ws + 55181312ull);        // 28*16 KB
    f16*         RpartH= (f16*)(ws + 55640064ull);          // 2*1 MB (ping-pong)
    float*       F     = (float*)(ws + 57737216ull);        // 2.24 KB

    constexpr size_t RPN = (size_t)128 * NDIM;   // one Rpart buffer (f16 elems)

    k_build_w0<<<dim3(16), dim3(256), 0, stream>>>(Bm, Dm, L, Wh);
    k_build_a<<<dim3(64 * 64), dim3(256), 0, stream>>>(A, C, L, AhSw, A8r, sAg);

    for (int r = 0; r < VAPPS; ++r) {
        const size_t in   = (size_t)r * SLAB;
        const size_t out_ = (size_t)(r + 1) * SLAB;
        const f16* rin  = RpartH + ((r + 1) & 1) * RPN;
        f16*       rout = RpartH + (r & 1) * RPN;
        k_stepVR<<<dim3(256), dim3(256), 0, stream>>>(
            AhSw, A8r, sAg, Wh + in, Wh + out_,
            C, rin, rout, gf + (size_t)r * NDIM, r);
    }

    k_fbatch<<<dim3(JT), dim3(256), 0, stream>>>(Wh, C, gf, F);
    k_conv<<<dim3(16), dim3(256), 0, stream>>>(F, u, yobs, Dm, out);
}

// Round 17
// 425.282 us; speedup vs baseline: 8.3718x; 1.0004x over previous
//
#include <hip/hip_runtime.h>
#include <math.h>

// Observer recurrence -> LTI Markov-parameter convolution.
//   A' = A - L*C, K = [B - L*D | L | h0], f_m = C A'^m K
//   y_t = f_t[9] + D*u_t + sum_j f_j . z_{t-1-j};  out = 3*tanh(y)
// Round-25: build_a store-coalescing. r16 disproved the load theory (float4
// loads, dur unchanged 41us @ 26% HBM, VALU 19%): the limiter is STORE
// request amplification -- swizzled-frag stores were 128B runs w/ gaps (2x)
// and int8 stores 64B segments @4KB stride (4x): request-equiv ~190MB ->
// ~30us, matching. New block shape: 16 rows x 1024 cols (1024 blocks = one
// row-tile x one kc-quarter). Every phase now writes 1KB/wave-instr:
//   loads: 1KB from one A row; int8: one full 1KB row segment/instr;
//   fp16 frags: a block's 32 kc-chunks of one tile are CONTIGUOUS in AhSw
//   (32KB/block, 1KB per chunk-instr).
// Arithmetic bit-identical to r16 (same fp32 A-L*C, same per-(row x 64col)
// scale = old per-block smax, same rintf/clamp/cvt); outputs byte-identical;
// chain kernels untouched (r13-exact) -> absmax must be 0.0390625.
// Predicted: build 41.4 -> ~18-23us; total 425.5 -> ~403-412.

constexpr int NDIM  = 4096;
constexpr int NC    = 10;         // live columns of K/W
constexpr int SLAB  = 16 * 4096;  // padded 16-col col-major slab (elements)
constexpr int JT    = 56;         // truncation length
constexpr int VAPPS = 28;         // V-chain applications (W_1..W_28)
constexpr int KC    = NDIM / 32;  // 128 k-chunks of 32
constexpr int TILES = NDIM / 16;  // 256 row-tiles of 16

typedef float    f32x4  __attribute__((ext_vector_type(4)));
typedef _Float16 h16x8  __attribute__((ext_vector_type(8)));
typedef _Float16 f16;

// ---------- build A' = A - L*C: fp16 swizzled frags + int8 plain + scales --
// Block = row-tile t (16 rows) x col-quarter cq (1024 cols). 256 threads.
// AhSw element (h16x8): idx = (tile*KC + kc)*64 + lane,
//   lane = mr + 16q holds A'[tile*16+mr][kc*32 + q*8 .. +7]
// A8r: plain row-major int8, q = round(x * 127 / groupmax(row, 64-col grp))
// sAg[row][g]: groupmax/127 for 64-col group g.
__global__ __launch_bounds__(256) void k_build_a(
        const float* __restrict__ A, const float* __restrict__ C,
        const float* __restrict__ L, h16x8* __restrict__ AhSw,
        signed char* __restrict__ A8r, float* __restrict__ sAg) {
    __shared__ float lds[16][1028];
    __shared__ float smax[16][16];
    const int tid  = threadIdx.x;
    const int wave = tid >> 6, lane = tid & 63;
    const int t  = blockIdx.x >> 2;       // row-tile
    const int cq = blockIdx.x & 3;        // col-quarter
    const int R0 = t * 16;
    const int C0 = cq * 1024;

    // load + A - L*C: per wave 4 rows; per pass 1KB contiguous from one row
    #pragma unroll
    for (int p = 0; p < 16; ++p) {
        const int row = wave * 4 + (p & 3);
        const int col = (p >> 2) * 256 + lane * 4;
        const float4 a  = *(const float4*)(A + (size_t)(R0 + row) * NDIM + C0 + col);
        const float4 cv = *(const float4*)(C + C0 + col);
        const float Li  = L[R0 + row];
        float4 v;
        v.x = a.x - Li * cv.x; v.y = a.y - Li * cv.y;
        v.z = a.z - Li * cv.z; v.w = a.w - Li * cv.w;
        *(float4*)&lds[row][col] = v;
    }
    __syncthreads();
    // group max: thread (r = tid>>4, g = tid&15) scans cols [g*64, g*64+64)
    {
        const int r = tid >> 4, g = tid & 15;
        float mx = 0.0f;
        #pragma unroll 8
        for (int c = 0; c < 64; ++c) mx = fmaxf(mx, fabsf(lds[r][g * 64 + c]));
        smax[r][g] = mx;
        sAg[(size_t)(R0 + r) * 64 + cq * 16 + g] = mx / 127.0f;
    }
    __syncthreads();
    // int8 emission: per wave 4 rows, one full 1KB row segment per instr
    #pragma unroll
    for (int p = 0; p < 4; ++p) {
        const int row = wave * 4 + p;
        const int c0  = lane * 16;
        const float mx  = smax[row][lane >> 2];
        const float inv = mx > 0.0f ? 127.0f / mx : 0.0f;
        union { int4 v; signed char c[16]; } uo;
        #pragma unroll
        for (int j4 = 0; j4 < 4; ++j4) {
            const float4 x = *(const float4*)&lds[row][c0 + j4 * 4];
            const float xs[4] = { x.x, x.y, x.z, x.w };
            #pragma unroll
            for (int j = 0; j < 4; ++j) {
                int qv = (int)rintf(xs[j] * inv);
                qv = qv > 127 ? 127 : (qv < -127 ? -127 : qv);
                uo.c[j4 * 4 + j] = (signed char)qv;
            }
        }
        *(int4*)(A8r + (size_t)(R0 + row) * NDIM + C0 + c0) = uo.v;
    }
    // fp16 frag emission: per wave 8 kc-chunks, 1KB contiguous per chunk
    #pragma unroll
    for (int cc = 0; cc < 8; ++cc) {
        const int c  = wave * 8 + cc;        // kc-local 0..31
        const int mr = lane & 15, q = lane >> 4;
        union { h16x8 v; f16 h[8]; } pk;
        #pragma unroll
        for (int j = 0; j < 8; ++j) pk.h[j] = (f16)lds[mr][c * 32 + q * 8 + j];
        AhSw[((size_t)t * KC + cq * 32 + c) * 64 + lane] = pk.v;
    }
}

// ---------- W0 = K = [B-L*D | L | ones | 0-pad], fp16 ----------
__global__ __launch_bounds__(256) void k_build_w0(
        const float* __restrict__ Bm, const float* __restrict__ Dm,
        const float* __restrict__ L, f16* __restrict__ Wh) {
    int k = blockIdx.x * blockDim.x + threadIdx.x; // < 4096
    float Lk = L[k];
    float col[16];
    #pragma unroll
    for (int c = 0; c < 8; ++c) col[c] = Bm[k * 8 + c] - Lk * Dm[c];
    col[8] = Lk; col[9] = 1.0f;
    #pragma unroll
    for (int c = 10; c < 16; ++c) col[c] = 0.0f;
    #pragma unroll
    for (int c = 0; c < 16; ++c) Wh[c * NDIM + k] = (f16)col[c];
}

// ---------- fused step: V-role (blocks 0..127) + R-role (blocks 128..255) --
// V: block tp owns tiles 2tp,2tp+1; wave w: tile 2tp+(w>>1), k-half (w&1);
//    fp16 MFMA, dead-col skip (r6/r12 exact). Epilogue writes Wh only.
// R: block t owns rows [32t,32t+32): reduce 128 fp16 partials, emit g_r,
//    next partials from int8 A8r with per-group scales (gsc staged in LDS).
__global__ __launch_bounds__(256) void k_stepVR(
        const h16x8* __restrict__ AhSw,
        const signed char* __restrict__ A8r, const float* __restrict__ sAg,
        const f16* __restrict__ WhIn, f16* __restrict__ WhOut,
        const float* __restrict__ Cvec,
        const f16* __restrict__ RpartIn, f16* __restrict__ RpartOut,
        float* __restrict__ gfSlot, const int r) {
    const int tid = threadIdx.x;

    if (blockIdx.x < 128) {
        // ---------------- V role ----------------
        __shared__ f32x4 red[4][64];
        const int lane = tid & 63, wave = tid >> 6;
        const int mr   = lane & 15, q = lane >> 4;
        const int tp   = blockIdx.x;
        const int tile = tp * 2 + (wave >> 1);
        const int kh   = wave & 1;
        const int k0   = kh * 2048;
        const bool liveB = (mr < NC);
        const h16x8* a8 = AhSw + ((size_t)tile * KC + (size_t)kh * 64) * 64 + lane;
        const h16x8* b8 = (const h16x8*)WhIn + (((size_t)mr * NDIM + k0) >> 3) + q;

        f32x4 acc0 = {0,0,0,0}, acc1 = {0,0,0,0};
        for (int it = 0; it < 8; ++it) {
            h16x8 ra[8], rb[8];
            #pragma unroll
            for (int s = 0; s < 8; ++s) rb[s] = (h16x8){0,0,0,0,0,0,0,0};
            #pragma unroll
            for (int s = 0; s < 8; ++s) {
                const int c = it * 8 + s;           // kc-local 0..63
                ra[s] = a8[(size_t)c * 64];
            }
            if (liveB) {
                #pragma unroll
                for (int s = 0; s < 8; ++s) {
                    const int c = it * 8 + s;
                    rb[s] = b8[c * 4];
                }
            }
            #pragma unroll
            for (int s = 0; s < 8; ++s) {
                if (s & 1) acc1 = __builtin_amdgcn_mfma_f32_16x16x32_f16(ra[s], rb[s], acc1, 0, 0, 0);
                else       acc0 = __builtin_amdgcn_mfma_f32_16x16x32_f16(ra[s], rb[s], acc0, 0, 0, 0);
            }
        }
        red[wave][lane] = acc0 + acc1;
        __syncthreads();
        if (tid < 128) {
            const int half = tid >> 6;          // 0: tile 2tp, 1: tile 2tp+1
            const int l    = tid & 63;
            f32x4 v = red[half * 2][l] + red[half * 2 + 1][l];
            const int col = l & 15;
            if (col < NC) {
                const int row0 = (tp * 2 + half) * 16;
                const int rb0  = row0 + ((l >> 4) << 2);
                #pragma unroll
                for (int i = 0; i < 4; ++i)
                    WhOut[col * NDIM + rb0 + i] = (f16)v[i];
            }
        }
    } else {
        // ---------------- R role ----------------
        __shared__ f16   rp[128][32];   // fp16 partials, 8 KB
        __shared__ float g8[8][33];
        __shared__ float gs[32];
        __shared__ float gsc[32][64];   // gs[rr] * sAg[row][g], 8 KB
        const int t = blockIdx.x - 128;  // rows [32t, 32t+32)

        if (r == 0) {
            if (tid < 32) gs[tid] = Cvec[t * 32 + tid];
        } else {
            {
                const int p = tid >> 1, half = tid & 1;
                const h16x8* src = (const h16x8*)(RpartIn
                        + (size_t)p * NDIM + t * 32 + half * 16);
                h16x8 v0 = src[0], v1 = src[1];
                *(h16x8*)&rp[p][half * 16]     = v0;
                *(h16x8*)&rp[p][half * 16 + 8] = v1;
            }
            __syncthreads();
            {
                const int c = tid & 31, g = tid >> 5;   // 8 groups x 32 cols
                float s = 0.0f;
                #pragma unroll
                for (int j = 0; j < 16; ++j) s += (float)rp[g * 16 + j][c];
                g8[g][c] = s;
            }
            __syncthreads();
            if (tid < 32) {
                float s = 0.0f;
                #pragma unroll
                for (int g = 0; g < 8; ++g) s += g8[g][tid];
                gs[tid] = s;
            }
        }
        __syncthreads();
        if (tid < 32) gfSlot[t * 32 + tid] = gs[tid];

        if (r < VAPPS - 1) {
            // stage gs[rr] * sAg[(32t+rr)][g] into LDS
            #pragma unroll
            for (int i = 0; i < 8; ++i) {
                const int idx = tid + i * 256;          // 0..2047
                const int rr = idx >> 6, g = idx & 63;
                gsc[rr][g] = gs[rr] * sAg[(size_t)(t * 32 + rr) * 64 + g];
            }
            __syncthreads();
            const int c0 = tid * 16;            // 16 cols per thread
            const int g0 = tid >> 2;            // col-group (fixed per thread)
            float acc[16] = {};
            const int4* arow = (const int4*)(A8r + (size_t)(t * 32) * NDIM + c0);
            for (int rr = 0; rr < 32; ++rr) {
                const int4 v = arow[(size_t)rr * (NDIM / 16)];
                const float gm = gsc[rr][g0];
                const int w0 = v.x, w1 = v.y, w2 = v.z, w3 = v.w;
                #pragma unroll
                for (int b = 0; b < 4; ++b) {
                    acc[b]      += gm * (float)((w0 << (24 - 8 * b)) >> 24);
                    acc[4 + b]  += gm * (float)((w1 << (24 - 8 * b)) >> 24);
                    acc[8 + b]  += gm * (float)((w2 << (24 - 8 * b)) >> 24);
                    acc[12 + b] += gm * (float)((w3 << (24 - 8 * b)) >> 24);
                }
            }
            union { h16x8 h; int4 i4; } o0, o1;
            #pragma unroll
            for (int j = 0; j < 8; ++j) {
                o0.h[j] = (f16)acc[j];
                o1.h[j] = (f16)acc[8 + j];
            }
            h16x8* op = (h16x8*)(RpartOut + (size_t)t * NDIM + c0);
            op[0] = o0.h;
            op[1] = o1.h;
        }
    }
}

// ---------- f_m for all m: m<=28 via C.W_m, m=28+i via g_i.W_28 ----------
__global__ __launch_bounds__(256) void k_fbatch(
        const f16* __restrict__ Wh, const float* __restrict__ C,
        const float* __restrict__ gf, float* __restrict__ F) {
    const int m = blockIdx.x;             // 0..JT-1
    const f16* W;
    const float* vec;
    if (m <= VAPPS) { W = Wh + (size_t)m * SLAB;     vec = C; }
    else            { W = Wh + (size_t)VAPPS * SLAB; vec = gf + (size_t)(m - VAPPS) * NDIM; }
    const int tid = threadIdx.x, lane = tid & 63, wave = tid >> 6;
    float acc[NC] = {};
    for (int k = tid; k < NDIM; k += 256) {
        float ck = vec[k];
        #pragma unroll
        for (int c = 0; c < NC; ++c) acc[c] += ck * (float)W[c * NDIM + k];
    }
    __shared__ float red[4][NC];
    #pragma unroll
    for (int c = 0; c < NC; ++c) {
        float s = acc[c];
        #pragma unroll
        for (int off = 32; off > 0; off >>= 1) s += __shfl_down(s, off);
        if (lane == 0) red[wave][c] = s;
    }
    __syncthreads();
    if (tid < NC) F[m * NC + tid] = red[0][tid] + red[1][tid] + red[2][tid] + red[3][tid];
}

// ---------- causal convolution + tanh epilogue ----------
__global__ __launch_bounds__(256) void k_conv(
        const float* __restrict__ F, const float* __restrict__ u,
        const float* __restrict__ yobs, const float* __restrict__ Dm,
        float* __restrict__ out) {
    __shared__ float Fl[JT * NC];
    __shared__ float zw[(JT + 256) * 9];
    const int tid = threadIdx.x;
    const int t0  = blockIdx.x * 256;
    for (int idx = tid; idx < JT * NC; idx += 256) Fl[idx] = F[idx];
    for (int idx = tid; idx < (JT + 256) * 9; idx += 256) {
        int k = idx / 9, c = idx - k * 9;
        int s = t0 - JT + k;
        float v = 0.0f;
        if (s >= 0 && s < NDIM) v = (c < 8) ? u[c * NDIM + s] : yobs[s];
        zw[idx] = v;
    }
    __syncthreads();
    const int t = t0 + tid;
    float y = (t < JT) ? Fl[t * NC + 9] : 0.0f; // C A'^t h0 term (truncated)
    #pragma unroll
    for (int c = 0; c < 8; ++c) y += Dm[c] * u[c * NDIM + t];
    for (int j = 0; j < JT; ++j) { // s = t-1-j; s<0 hits zero pad
        const float* fj = Fl + j * NC;
        const float* zz = zw + (tid + JT - 1 - j) * 9;
        float p = 0.0f;
        #pragma unroll
        for (int c = 0; c < 9; ++c) p += fj[c] * zz[c];
        y += p;
    }
    out[t] = 3.0f * tanhf(y);
}

extern "C" void kernel_launch(void* const* d_in, const int* in_sizes, int n_in,
                              void* d_out, int out_size, void* d_ws, size_t ws_size,
                              hipStream_t stream) {
    const float* u    = (const float*)d_in[0];
    const float* yobs = (const float*)d_in[1];
    const float* A    = (const float*)d_in[2];
    const float* Bm   = (const float*)d_in[3];
    const float* C    = (const float*)d_in[4];
    const float* Dm   = (const float*)d_in[5];
    const float* L    = (const float*)d_in[6];
    float* out = (float*)d_out;

    // workspace layout (~58 MB)
    char* ws = (char*)d_ws;
    h16x8*       AhSw  = (h16x8*)ws;                        // 32 MB
    signed char* A8r   = (signed char*)(ws + 33554432ull);  // 16 MB
    float*       sAg   = (float*)(ws + 50331648ull);        // 1 MB (4096x64)
    f16*         Wh    = (f16*)(ws + 51380224ull);          // 29*128 KB
    float*       gf    = (float*)(ws + 55181312ull);        // 28*16 KB
    f16*         RpartH= (f16*)(ws + 55640064ull);          // 2*1 MB (ping-pong)
    float*       F     = (float*)(ws + 57737216ull);        // 2.24 KB

    constexpr size_t RPN = (size_t)128 * NDIM;   // one Rpart buffer (f16 elems)

    k_build_w0<<<dim3(16), dim3(256), 0, stream>>>(Bm, Dm, L, Wh);
    k_build_a<<<dim3(TILES * 4), dim3(256), 0, stream>>>(A, C, L, AhSw, A8r, sAg);

    for (int r = 0; r < VAPPS; ++r) {
        const size_t in   = (size_t)r * SLAB;
        const size_t out_ = (size_t)(r + 1) * SLAB;
        const f16* rin  = RpartH + ((r + 1) & 1) * RPN;
        f16*       rout = RpartH + (r & 1) * RPN;
        k_stepVR<<<dim3(256), dim3(256), 0, stream>>>(
            AhSw, A8r, sAg, Wh + in, Wh + out_,
            C, rin, rout, gf + (size_t)r * NDIM, r);
    }

    k_fbatch<<<dim3(JT), dim3(256), 0, stream>>>(Wh, C, gf, F);
    k_conv<<<dim3(16), dim3(256), 0, stream>>>(F, u, yobs, Dm, out);
}